// Round 7
// baseline (37.517 us; speedup 1.0000x reference)
//
#include <hip/hip_runtime.h>

// Focal loss: out[0]=loss_pos, out[1]=loss_neg, out[2]=count_pos, out[3]=count_neg
// ALPHA=2, FPN_POS_FACTOR=(2,1), FPN_NEG_FACTOR=(2,1), ANCHOR_POS_FACTOR={1,1}
// logit0: [8,2,64,128,128] f32 (16,777,216), logit1: [8,2,32,64,64] f32 (2,097,152)
//
// R6 post-mortem: VGPR=28 (loads sunk again), VALU 16%, HBM 20% -> latency-
// bound. R7: persistent exact-cover grid (2048 blocks, 524288 threads):
// L0 = exactly 8 quads/thread, L1 = exactly 1 quad/thread. Depth-1 prefetch
// loop (load i+1 before computing i) + L1 pair in flight during iter0.

#define LOG2E 1.44269504088896340736f
#define LN2   0.69314718055994530942f

__device__ __forceinline__ float exp2_hw(float x) { return __builtin_amdgcn_exp2f(x); }
__device__ __forceinline__ float log2_hw(float x) { return __builtin_amdgcn_logf(x); }  // v_log_f32 = log2
__device__ __forceinline__ float rcp_hw(float x)  { return __builtin_amdgcn_rcpf(x); }

// w = sigmoid(x)^2*[g==-1]; loss += softplus(x)*w; count += w
__device__ __forceinline__ void neg_elem(float x, float g, float& lsum, float& csum) {
    float z  = fmaxf(x * LOG2E, -43.0f);    // clamp: below this weight < 1e-26
    float t  = exp2_hw(-z);                 // e^{-x}
    float u  = 1.0f + t;
    float r  = rcp_hw(u);                   // sigmoid(x)
    float w  = (g == -1.0f) ? r * r : 0.0f; // prob^2 * negmask
    float sp = LN2 * (z + log2_hw(u));      // softplus(x)
    csum += w;
    lsum += sp * w;
}

__device__ __forceinline__ void neg_quad(float4 x4, float4 g4, float& lsum, float& csum) {
    neg_elem(x4.x, g4.x, lsum, csum);
    neg_elem(x4.y, g4.y, lsum, csum);
    neg_elem(x4.z, g4.z, lsum, csum);
    neg_elem(x4.w, g4.w, lsum, csum);
}

// Persistent grid: T = gridDim.x*256 threads; L0 quads = 8*T, L1 quads = T.
// Grid-stride (stride T) over L0 with depth-1 prefetch; one L1 quad each.
__global__ void __launch_bounds__(256, 4) neg_loss_kernel(
        const float4* __restrict__ x0, const float4* __restrict__ g0, int n0q,
        const float4* __restrict__ x1, const float4* __restrict__ g1, int n1q,
        float2* __restrict__ ws) {
    const int T = gridDim.x * 256;
    const int t = blockIdx.x * 256 + threadIdx.x;

    // Issue 4 independent loads up front: L1 pair + L0 iter0 pair.
    float4 x1q = x1[t];
    float4 g1q = g1[t];
    float4 xa  = x0[t];
    float4 ga  = g0[t];

    float l1 = 0.0f, l0 = 0.0f, csum = 0.0f;
    neg_quad(x1q, g1q, l1, csum);           // compute L1 while iter0 in flight

    const int iters = n0q / T;              // exactly 8
    #pragma unroll 8
    for (int i = 0; i < iters; ++i) {
        float4 xn, gn;
        if (i + 1 < iters) {                // prefetch iter i+1 before compute i
            xn = x0[t + (i + 1) * T];
            gn = g0[t + (i + 1) * T];
        }
        neg_quad(xa, ga, l0, csum);
        xa = xn; ga = gn;
    }
    float lsum = 2.0f * l0 + l1;            // FPN_NEG_FACTOR

    #pragma unroll
    for (int off = 32; off > 0; off >>= 1) {
        lsum += __shfl_down(lsum, off);
        csum += __shfl_down(csum, off);
    }
    __shared__ float sl[4], sc[4];
    const int wav = threadIdx.x >> 6, lane = threadIdx.x & 63;
    if (lane == 0) { sl[wav] = lsum; sc[wav] = csum; }
    __syncthreads();
    if (threadIdx.x == 0) {
        ws[blockIdx.x] = make_float2(sl[0] + sl[1] + sl[2] + sl[3],
                                     sc[0] + sc[1] + sc[2] + sc[3]);
    }
}

// One block, 1024 threads: positive (gathered) term + reduce ws partials.
__global__ void __launch_bounds__(1024) finalize_kernel(
        const float* __restrict__ logit0, const int* __restrict__ coord0,
        const float* __restrict__ logit1, const int* __restrict__ coord1,
        const float2* __restrict__ ws, int nblk,
        float* __restrict__ out) {
    const int j = threadIdx.x;
    float lp = 0.0f, cp = 0.0f;
    {
        const int level = (j >= 512);
        const int jj = level ? (j - 512) : j;
        const int b = jj >> 6;  // P = 64
        const int* cptr = (level ? coord1 : coord0) + jj * 4;
        int c0 = cptr[0], c1 = cptr[1], c2 = cptr[2], c3 = cptr[3];
        const bool v = (c0 > -1);
        const float valid = v ? 1.0f : 0.0f;
        if (!v) { c0 = 0; c1 = 0; c2 = 0; c3 = 0; }
        long off;
        const float* lg;
        float posf;
        if (!level) {
            off = ((((long)b * 2 + c0) * 64 + c1) * 128 + c2) * 128 + c3;  // [8][2][64][128][128]
            lg = logit0; posf = 2.0f;
        } else {
            off = ((((long)b * 2 + c0) * 32 + c1) * 64 + c2) * 64 + c3;   // [8][2][32][64][64]
            lg = logit1; posf = 1.0f;
        }
        const float x = lg[off];
        // w = (1-sigmoid(x))^2 * valid;  -log_sigmoid(x) = softplus(-x)
        float z  = fmaxf(-x * LOG2E, -43.0f);
        float t  = exp2_hw(-z);                 // e^{x}
        float u  = 1.0f + t;
        float r  = rcp_hw(u);                   // 1 - sigmoid(x)
        float w  = r * r * valid;
        float sp = LN2 * (z + log2_hw(u));      // softplus(-x)
        lp = sp * w * posf;                     // w2 = ANCHOR_POS_FACTOR = 1
        cp = w;
    }
    float ln = 0.0f, cn = 0.0f;
    for (int i = j; i < nblk; i += 1024) {
        float2 p = ws[i];
        ln += p.x;
        cn += p.y;
    }
    #pragma unroll
    for (int off = 32; off > 0; off >>= 1) {
        lp += __shfl_down(lp, off);
        cp += __shfl_down(cp, off);
        ln += __shfl_down(ln, off);
        cn += __shfl_down(cn, off);
    }
    __shared__ float sl[16], sc[16], sln[16], scn[16];
    int wav = threadIdx.x >> 6, lane = threadIdx.x & 63;
    if (lane == 0) { sl[wav] = lp; sc[wav] = cp; sln[wav] = ln; scn[wav] = cn; }
    __syncthreads();
    if (threadIdx.x == 0) {
        float tl = 0.0f, tc = 0.0f, tln = 0.0f, tcn = 0.0f;
        #pragma unroll
        for (int i = 0; i < 16; ++i) { tl += sl[i]; tc += sc[i]; tln += sln[i]; tcn += scn[i]; }
        out[0] = tl;
        out[1] = tln;
        out[2] = tc;
        out[3] = tcn;
    }
}

extern "C" void kernel_launch(void* const* d_in, const int* in_sizes, int n_in,
                              void* d_out, int out_size, void* d_ws, size_t ws_size,
                              hipStream_t stream) {
    const float* logit0 = (const float*)d_in[0];
    const float* logit1 = (const float*)d_in[1];
    const float* gt0    = (const float*)d_in[2];
    const float* gt1    = (const float*)d_in[3];
    const int*   coord0 = (const int*)d_in[4];
    const int*   coord1 = (const int*)d_in[5];
    float* out = (float*)d_out;
    float2* ws = (float2*)d_ws;

    const int n0 = in_sizes[0];  // 16,777,216 floats
    const int n1 = in_sizes[1];  //  2,097,152 floats
    const int n0q = n0 >> 2;     // 4,194,304 quads = 8 * 524288
    const int n1q = n1 >> 2;     //   524,288 quads = 1 * 524288
    const int nblk = n1q / 256;  // 2048 blocks -> T = 524288 threads

    neg_loss_kernel<<<nblk, 256, 0, stream>>>(
        (const float4*)logit0, (const float4*)gt0, n0q,
        (const float4*)logit1, (const float4*)gt1, n1q, ws);
    finalize_kernel<<<1, 1024, 0, stream>>>(
        logit0, coord0, logit1, coord1, ws, nblk, out);
}